// Round 2
// baseline (2258.861 us; speedup 1.0000x reference)
//
#include <hip/hip_runtime.h>
#include <math.h>

#define B_   4
#define N_   4096
#define C_   256
#define NH   8      // heads
#define D_   32     // head dim
#define PL_  256    // pooled length
#define IMG  64     // H = W = 64

__device__ __forceinline__ float gelu_f(float v) {
    return 0.5f * v * (1.0f + erff(v * 0.70710678118654752440f));
}

// ---------------------------------------------------------------------------
// Generic fp32 tiled GEMM: out[M,N] = A[M,K] @ W[K,N] + bias, ACT=1 -> GELU
// BM=BN=128, BK=8, 256 threads, 8x8 microtile. M%128==0, N%128==0, K%8==0.
// ---------------------------------------------------------------------------
template<int ACT>
__global__ __launch_bounds__(256) void gemm128(const float* __restrict__ A,
                                               const float* __restrict__ W,
                                               const float* __restrict__ bias,
                                               float* __restrict__ out,
                                               int M, int N, int K)
{
    __shared__ float As[8][132];
    __shared__ float Bs[8][128];
    const int t  = threadIdx.x;
    const int tx = t & 15, ty = t >> 4;
    const int m0 = blockIdx.y * 128, n0 = blockIdx.x * 128;

    float acc[8][8];
    #pragma unroll
    for (int i = 0; i < 8; ++i)
        #pragma unroll
        for (int j = 0; j < 8; ++j) acc[i][j] = 0.f;

    const int arow = t >> 1, akq = t & 1;   // A: 128 rows x 2 float4 of k
    const int brow = t >> 5, bq  = t & 31;  // B: 8 rows x 32 float4 of n
    for (int k0 = 0; k0 < K; k0 += 8) {
        float4 a4 = *(const float4*)&A[(size_t)(m0 + arow) * K + k0 + akq * 4];
        As[akq*4+0][arow] = a4.x;
        As[akq*4+1][arow] = a4.y;
        As[akq*4+2][arow] = a4.z;
        As[akq*4+3][arow] = a4.w;
        *(float4*)&Bs[brow][bq*4] =
            *(const float4*)&W[(size_t)(k0 + brow) * N + n0 + bq*4];
        __syncthreads();
        #pragma unroll
        for (int kk = 0; kk < 8; ++kk) {
            float4 a0 = *(const float4*)&As[kk][ty*8];
            float4 a1 = *(const float4*)&As[kk][ty*8+4];
            float4 b0 = *(const float4*)&Bs[kk][tx*8];
            float4 b1 = *(const float4*)&Bs[kk][tx*8+4];
            float av[8] = {a0.x,a0.y,a0.z,a0.w,a1.x,a1.y,a1.z,a1.w};
            float bv[8] = {b0.x,b0.y,b0.z,b0.w,b1.x,b1.y,b1.z,b1.w};
            #pragma unroll
            for (int i = 0; i < 8; ++i)
                #pragma unroll
                for (int j = 0; j < 8; ++j)
                    acc[i][j] = fmaf(av[i], bv[j], acc[i][j]);
        }
        __syncthreads();
    }
    #pragma unroll
    for (int i = 0; i < 8; ++i) {
        int m = m0 + ty*8 + i;
        #pragma unroll
        for (int j0 = 0; j0 < 8; j0 += 4) {
            int n = n0 + tx*8 + j0;
            float4 r;
            r.x = acc[i][j0+0] + bias[n+0];
            r.y = acc[i][j0+1] + bias[n+1];
            r.z = acc[i][j0+2] + bias[n+2];
            r.w = acc[i][j0+3] + bias[n+3];
            if (ACT == 1) {
                r.x = gelu_f(r.x); r.y = gelu_f(r.y);
                r.z = gelu_f(r.z); r.w = gelu_f(r.w);
            }
            *(float4*)&out[(size_t)m * N + n] = r;
        }
    }
}

// ---------------------------------------------------------------------------
// pool_ln: 4x4 mean-pool of gelu'd sr buffer + LayerNorm -> xs[B*PL, C]
// one block per (b, p); 256 threads = channels.
// ---------------------------------------------------------------------------
__global__ __launch_bounds__(256) void pool_ln_kernel(const float* __restrict__ sr,
                                                      const float* __restrict__ g,
                                                      const float* __restrict__ bb,
                                                      float* __restrict__ xs)
{
    __shared__ float red[256];
    int bp = blockIdx.x;
    int b = bp >> 8, p = bp & 255;
    int i0 = p >> 4, j0 = p & 15;
    int c = threadIdx.x;
    float s = 0.f;
    #pragma unroll
    for (int di = 0; di < 4; ++di)
        #pragma unroll
        for (int dj = 0; dj < 4; ++dj) {
            int n = (i0*4 + di) * IMG + (j0*4 + dj);
            s += sr[((size_t)b * N_ + n) * C_ + c];
        }
    s *= (1.f / 16.f);
    red[c] = s; __syncthreads();
    for (int o = 128; o > 0; o >>= 1) { if (c < o) red[c] += red[c+o]; __syncthreads(); }
    float mean = red[0] * (1.f/256.f);
    __syncthreads();
    float dcen = s - mean;
    red[c] = dcen * dcen; __syncthreads();
    for (int o = 128; o > 0; o >>= 1) { if (c < o) red[c] += red[c+o]; __syncthreads(); }
    float var = red[0] * (1.f/256.f);
    float outv = dcen * rsqrtf(var + 1e-5f) * g[c] + bb[c];
    xs[(size_t)bp * C_ + c] = outv;
}

// ---------------------------------------------------------------------------
// cpb: t = relu(rct @ w1 + b1) @ w2 + b2, stored transposed tT[h][1024]
// one block (64 threads = 1 wave) per table row l.
// ---------------------------------------------------------------------------
__global__ __launch_bounds__(64) void cpb_kernel(const float* __restrict__ rct,
                                                 const float* __restrict__ w1,
                                                 const float* __restrict__ b1,
                                                 const float* __restrict__ w2,
                                                 const float* __restrict__ b2,
                                                 float* __restrict__ tT)
{
    int l = blockIdx.x;
    int lane = threadIdx.x;
    float c0 = rct[l*2+0], c1 = rct[l*2+1];
    float acc[8] = {0,0,0,0,0,0,0,0};
    for (int j = lane; j < 512; j += 64) {
        float hv = fmaxf(c0 * w1[j] + c1 * w1[512+j] + b1[j], 0.f);
        #pragma unroll
        for (int hh = 0; hh < 8; ++hh) acc[hh] += hv * w2[j*8 + hh];
    }
    #pragma unroll
    for (int o = 32; o > 0; o >>= 1)
        #pragma unroll
        for (int hh = 0; hh < 8; ++hh) acc[hh] += __shfl_xor(acc[hh], o, 64);
    if (lane < 8) tT[lane * 1024 + l] = acc[lane] + b2[lane];
}

// ---------------------------------------------------------------------------
// attn_simple: one block per (b,n); 8 heads x 32 lanes. Computes q_norm,
// q_scaled, all 265 logits (with on-the-fly k normalization), softmax in
// LDS, post-softmax learnable extras, and PV — all self-contained.
// Inputs are RAW (un-normalized) q / kv / kvp.
// ---------------------------------------------------------------------------
__global__ __launch_bounds__(256) void attn_simple(
    const float* __restrict__ q_g,    // raw q  [B*N,256]
    const float* __restrict__ kv_g,   // raw kv [B*N,512]  (k|v)
    const float* __restrict__ kvp_g,  // raw kvp[B*PL,512] (k|v)
    const float* __restrict__ tT,     // [8,1024]
    const int*   __restrict__ rpi,    // [N,PL]
    const float* __restrict__ rpb,    // [8,9]
    const float* __restrict__ qe,     // [8,32]
    const float* __restrict__ temp,   // [8]
    const float* __restrict__ lt,     // [8,32,9]
    const float* __restrict__ lb,     // [8,9]
    float* __restrict__ outp)         // [B*N,256]
{
    __shared__ float Ls[NH][268];

    const int bn   = blockIdx.x;
    const int b    = bn >> 12;
    const int n    = bn & (N_ - 1);
    const int hh   = threadIdx.x >> 5;
    const int lane = threadIdx.x & 31;
    const int y = n >> 6, x = n & 63;

    // ---- q_norm (per-lane d component) and q_scaled ----
    const float qraw = q_g[(size_t)bn * C_ + hh * D_ + lane];
    float qss = qraw * qraw;
    #pragma unroll
    for (int o = 16; o > 0; o >>= 1) qss += __shfl_xor(qss, o, 32);
    const float qn = qraw * rsqrtf(qss + 1e-12f);
    const float sp = log1pf(expf(temp[hh]));
    const int ci = 1 + (y > 0) + (y < IMG - 1);
    const int cj = 1 + (x > 0) + (x < IMG - 1);
    const float s2 = sp * logf((float)(ci * cj) + (float)PL_);
    const float qs = (qn + qe[hh * D_ + lane]) * s2;

    // ---- local logits (k normalized on the fly) ----
    #pragma unroll
    for (int l = 0; l < 9; ++l) {
        const int yy = y + l / 3 - 1, xx = x + l % 3 - 1;
        const bool valid = (yy >= 0 && yy < IMG && xx >= 0 && xx < IMG);
        float kval = 0.f;
        if (valid)
            kval = kv_g[((size_t)(b * N_ + yy * IMG + xx)) * 512 + hh * D_ + lane];
        float p1 = qs * kval;
        float p2 = kval * kval;
        #pragma unroll
        for (int o = 16; o > 0; o >>= 1) {
            p1 += __shfl_xor(p1, o, 32);
            p2 += __shfl_xor(p2, o, 32);
        }
        if (lane == 0)
            Ls[hh][l] = valid ? (p1 * rsqrtf(p2 + 1e-12f) + rpb[hh * 9 + l]) : -1e9f;
    }

    // ---- pooled logits ----
    #pragma unroll 2
    for (int p = 0; p < PL_; ++p) {
        const float kval = kvp_g[((size_t)(b * PL_ + p)) * 512 + hh * D_ + lane];
        float p1 = qs * kval;
        float p2 = kval * kval;
        #pragma unroll
        for (int o = 16; o > 0; o >>= 1) {
            p1 += __shfl_xor(p1, o, 32);
            p2 += __shfl_xor(p2, o, 32);
        }
        if (lane == 0)
            Ls[hh][9 + p] = p1 * rsqrtf(p2 + 1e-12f) + tT[hh * 1024 + rpi[n * PL_ + p]];
    }
    __syncthreads();

    // ---- softmax over 265 (strided lanes over LDS) ----
    float mx = -3.0e38f;
    for (int c = lane; c < 265; c += 32) mx = fmaxf(mx, Ls[hh][c]);
    #pragma unroll
    for (int o = 16; o > 0; o >>= 1) mx = fmaxf(mx, __shfl_xor(mx, o, 32));
    float sm = 0.f;
    for (int c = lane; c < 265; c += 32) {
        float e = expf(Ls[hh][c] - mx);
        Ls[hh][c] = e;
        sm += e;
    }
    #pragma unroll
    for (int o = 16; o > 0; o >>= 1) sm += __shfl_xor(sm, o, 32);
    const float inv = 1.f / sm;
    for (int c = lane; c < 265; c += 32) Ls[hh][c] *= inv;
    __syncthreads();

    // ---- post-softmax learnable extras on the 9 local weights ----
    #pragma unroll
    for (int l = 0; l < 9; ++l) {
        float p2 = qn * lt[hh * 288 + lane * 9 + l];
        #pragma unroll
        for (int o = 16; o > 0; o >>= 1) p2 += __shfl_xor(p2, o, 32);
        if (lane == 0) Ls[hh][l] += p2 + lb[hh * 9 + l];
    }
    __syncthreads();

    // ---- PV (lane = output dim) ----
    float acc = 0.f;
    #pragma unroll
    for (int l = 0; l < 9; ++l) {
        const int yy = y + l / 3 - 1, xx = x + l % 3 - 1;
        if (yy >= 0 && yy < IMG && xx >= 0 && xx < IMG)
            acc += Ls[hh][l] *
                   kv_g[((size_t)(b * N_ + yy * IMG + xx)) * 512 + 256 + hh * D_ + lane];
    }
    #pragma unroll 2
    for (int p = 0; p < PL_; ++p)
        acc += Ls[hh][9 + p] *
               kvp_g[((size_t)(b * PL_ + p)) * 512 + 256 + hh * D_ + lane];

    outp[(size_t)bn * C_ + hh * D_ + lane] = acc;
}

// ---------------------------------------------------------------------------
extern "C" void kernel_launch(void* const* d_in, const int* in_sizes, int n_in,
                              void* d_out, int out_size, void* d_ws, size_t ws_size,
                              hipStream_t stream) {
    const float* x    = (const float*)d_in[0];
    const float* rct  = (const float*)d_in[1];
    const int*   rpi  = (const int*)  d_in[2];
    const float* q_w  = (const float*)d_in[3];
    const float* q_b  = (const float*)d_in[4];
    const float* kv_w = (const float*)d_in[5];
    const float* kv_b = (const float*)d_in[6];
    const float* temp = (const float*)d_in[7];
    const float* qe   = (const float*)d_in[8];
    const float* sr_w = (const float*)d_in[9];
    const float* sr_b = (const float*)d_in[10];
    const float* ng   = (const float*)d_in[11];
    const float* nb   = (const float*)d_in[12];
    const float* c1w  = (const float*)d_in[13];
    const float* c1b  = (const float*)d_in[14];
    const float* c2w  = (const float*)d_in[15];
    const float* c2b  = (const float*)d_in[16];
    const float* rpb  = (const float*)d_in[17];
    const float* lt   = (const float*)d_in[18];
    const float* lb   = (const float*)d_in[19];
    const float* p_w  = (const float*)d_in[20];
    const float* p_b  = (const float*)d_in[21];
    float* out = (float*)d_out;

    float* ws = (float*)d_ws;
    const size_t MN = (size_t)B_ * N_;               // 16384
    float* buf_q   = ws;                             // [MN,256] raw q
    float* buf_kv  = buf_q   + MN * 256;             // [MN,512] raw k|v
    float* buf_sr  = buf_kv  + MN * 512;             // [MN,256] gelu(sr); later attn out
    float* buf_xs  = buf_sr  + MN * 256;             // [B*PL,256]
    float* buf_kvp = buf_xs  + (size_t)B_*PL_*256;   // [B*PL,512] raw k|v pooled
    float* buf_t   = buf_kvp + (size_t)B_*PL_*512;   // [8,1024]
    float* buf_pre = buf_sr;                         // alias: sr dead after pool_ln

    const int M = (int)MN;  // 16384

    gemm128<0><<<dim3(2,   M/128), 256, 0, stream>>>(x, q_w,  q_b,  buf_q,  M, 256, 256);
    gemm128<0><<<dim3(4,   M/128), 256, 0, stream>>>(x, kv_w, kv_b, buf_kv, M, 512, 256);
    gemm128<1><<<dim3(2,   M/128), 256, 0, stream>>>(x, sr_w, sr_b, buf_sr, M, 256, 256);

    pool_ln_kernel<<<B_ * PL_, 256, 0, stream>>>(buf_sr, ng, nb, buf_xs);
    gemm128<0><<<dim3(4, (B_*PL_)/128), 256, 0, stream>>>(buf_xs, kv_w, kv_b, buf_kvp,
                                                          B_*PL_, 512, 256);
    cpb_kernel<<<1024, 64, 0, stream>>>(rct, c1w, c1b, c2w, c2b, buf_t);

    attn_simple<<<B_ * N_, 256, 0, stream>>>(buf_q, buf_kv, buf_kvp, buf_t, rpi,
                                             rpb, qe, temp, lt, lb, buf_pre);

    gemm128<0><<<dim3(2,   M/128), 256, 0, stream>>>(buf_pre, p_w, p_b, out, M, 256, 256);
}

// Round 3
// 372.979 us; speedup vs baseline: 6.0563x; 6.0563x over previous
//
#include <hip/hip_runtime.h>
#include <math.h>

#define B_   4
#define N_   4096
#define C_   256
#define NH   8      // heads
#define D_   32     // head dim
#define PL_  256    // pooled length
#define IMG  64     // H = W = 64

typedef __attribute__((ext_vector_type(8))) short short8b;
typedef __attribute__((ext_vector_type(4))) float f32x4;
typedef unsigned short ushort_t;

__device__ __forceinline__ ushort_t f2bf(float f) {
    unsigned u = __float_as_uint(f);
    u += 0x7FFFu + ((u >> 16) & 1u);   // RTNE
    return (ushort_t)(u >> 16);
}
__device__ __forceinline__ float bf2f(ushort_t s) {
    return __uint_as_float(((unsigned)s) << 16);
}

__device__ __forceinline__ float gelu_f(float v) {
    return 0.5f * v * (1.0f + erff(v * 0.70710678118654752440f));
}

// ---------------------------------------------------------------------------
// Generic fp32 tiled GEMM (validated round 2): out = A@W + bias, ACT=1 GELU
// ---------------------------------------------------------------------------
template<int ACT>
__global__ __launch_bounds__(256) void gemm128(const float* __restrict__ A,
                                               const float* __restrict__ W,
                                               const float* __restrict__ bias,
                                               float* __restrict__ out,
                                               int M, int N, int K)
{
    __shared__ float As[8][132];
    __shared__ float Bs[8][128];
    const int t  = threadIdx.x;
    const int tx = t & 15, ty = t >> 4;
    const int m0 = blockIdx.y * 128, n0 = blockIdx.x * 128;

    float acc[8][8];
    #pragma unroll
    for (int i = 0; i < 8; ++i)
        #pragma unroll
        for (int j = 0; j < 8; ++j) acc[i][j] = 0.f;

    const int arow = t >> 1, akq = t & 1;
    const int brow = t >> 5, bq  = t & 31;
    for (int k0 = 0; k0 < K; k0 += 8) {
        float4 a4 = *(const float4*)&A[(size_t)(m0 + arow) * K + k0 + akq * 4];
        As[akq*4+0][arow] = a4.x;
        As[akq*4+1][arow] = a4.y;
        As[akq*4+2][arow] = a4.z;
        As[akq*4+3][arow] = a4.w;
        *(float4*)&Bs[brow][bq*4] =
            *(const float4*)&W[(size_t)(k0 + brow) * N + n0 + bq*4];
        __syncthreads();
        #pragma unroll
        for (int kk = 0; kk < 8; ++kk) {
            float4 a0 = *(const float4*)&As[kk][ty*8];
            float4 a1 = *(const float4*)&As[kk][ty*8+4];
            float4 b0 = *(const float4*)&Bs[kk][tx*8];
            float4 b1 = *(const float4*)&Bs[kk][tx*8+4];
            float av[8] = {a0.x,a0.y,a0.z,a0.w,a1.x,a1.y,a1.z,a1.w};
            float bv[8] = {b0.x,b0.y,b0.z,b0.w,b1.x,b1.y,b1.z,b1.w};
            #pragma unroll
            for (int i = 0; i < 8; ++i)
                #pragma unroll
                for (int j = 0; j < 8; ++j)
                    acc[i][j] = fmaf(av[i], bv[j], acc[i][j]);
        }
        __syncthreads();
    }
    #pragma unroll
    for (int i = 0; i < 8; ++i) {
        int m = m0 + ty*8 + i;
        #pragma unroll
        for (int j0 = 0; j0 < 8; j0 += 4) {
            int n = n0 + tx*8 + j0;
            float4 r;
            r.x = acc[i][j0+0] + bias[n+0];
            r.y = acc[i][j0+1] + bias[n+1];
            r.z = acc[i][j0+2] + bias[n+2];
            r.w = acc[i][j0+3] + bias[n+3];
            if (ACT == 1) {
                r.x = gelu_f(r.x); r.y = gelu_f(r.y);
                r.z = gelu_f(r.z); r.w = gelu_f(r.w);
            }
            *(float4*)&out[(size_t)m * N + n] = r;
        }
    }
}

// ---------------------------------------------------------------------------
// pool_ln (validated round 2)
// ---------------------------------------------------------------------------
__global__ __launch_bounds__(256) void pool_ln_kernel(const float* __restrict__ sr,
                                                      const float* __restrict__ g,
                                                      const float* __restrict__ bb,
                                                      float* __restrict__ xs)
{
    __shared__ float red[256];
    int bp = blockIdx.x;
    int b = bp >> 8, p = bp & 255;
    int i0 = p >> 4, j0 = p & 15;
    int c = threadIdx.x;
    float s = 0.f;
    #pragma unroll
    for (int di = 0; di < 4; ++di)
        #pragma unroll
        for (int dj = 0; dj < 4; ++dj) {
            int n = (i0*4 + di) * IMG + (j0*4 + dj);
            s += sr[((size_t)b * N_ + n) * C_ + c];
        }
    s *= (1.f / 16.f);
    red[c] = s; __syncthreads();
    for (int o = 128; o > 0; o >>= 1) { if (c < o) red[c] += red[c+o]; __syncthreads(); }
    float mean = red[0] * (1.f/256.f);
    __syncthreads();
    float dcen = s - mean;
    red[c] = dcen * dcen; __syncthreads();
    for (int o = 128; o > 0; o >>= 1) { if (c < o) red[c] += red[c+o]; __syncthreads(); }
    float var = red[0] * (1.f/256.f);
    float outv = dcen * rsqrtf(var + 1e-5f) * g[c] + bb[c];
    xs[(size_t)bp * C_ + c] = outv;
}

// ---------------------------------------------------------------------------
// cpb (validated round 2): tT[h][1024]
// ---------------------------------------------------------------------------
__global__ __launch_bounds__(64) void cpb_kernel(const float* __restrict__ rct,
                                                 const float* __restrict__ w1,
                                                 const float* __restrict__ b1,
                                                 const float* __restrict__ w2,
                                                 const float* __restrict__ b2,
                                                 float* __restrict__ tT)
{
    int l = blockIdx.x;
    int lane = threadIdx.x;
    float c0 = rct[l*2+0], c1 = rct[l*2+1];
    float acc[8] = {0,0,0,0,0,0,0,0};
    for (int j = lane; j < 512; j += 64) {
        float hv = fmaxf(c0 * w1[j] + c1 * w1[512+j] + b1[j], 0.f);
        #pragma unroll
        for (int hh = 0; hh < 8; ++hh) acc[hh] += hv * w2[j*8 + hh];
    }
    #pragma unroll
    for (int o = 32; o > 0; o >>= 1)
        #pragma unroll
        for (int hh = 0; hh < 8; ++hh) acc[hh] += __shfl_xor(acc[hh], o, 64);
    if (lane < 8) tT[lane * 1024 + l] = acc[lane] + b2[lane];
}

// ---------------------------------------------------------------------------
// attn_mfma: one block per (b, h, 64-row tile). 4 waves; wave w owns rows
// w*16..w*16+15 (one 16-row MFMA M-tile).
// Phase 0: stage normalized Kp (bf16, [256][32] chunk-swizzled), Vp^T (bf16
//          [32][264]), q_scaled rows (bf16 [64][32] swizzled).
// Phase 1: local 9 logits + learnable extras via lane-tasks (f32).
// Phase 2: QK^T pool logits via 16 MFMAs, bias gathered into C-in.
// Phase 3: joint softmax over 9+256 fully in-register; pool weights -> LDS
//          bf16 [64][264]; local weights finalized (+extras) in f32 LDS.
// Phase 4: PV pool via 16 MFMAs + local PV scalar; store f32.
// ---------------------------------------------------------------------------
__global__ __launch_bounds__(256, 2) void attn_mfma(
    const float* __restrict__ q_g,    // raw q  [B*N,256]
    const float* __restrict__ kv_g,   // raw kv [B*N,512]
    const float* __restrict__ kvp_g,  // raw kvp[B*PL,512]
    const float* __restrict__ tT,     // [8,1024]
    const int*   __restrict__ rpi,    // [N,PL]
    const float* __restrict__ rpb,    // [8,9]
    const float* __restrict__ qe,     // [8,32]
    const float* __restrict__ temp,   // [8]
    const float* __restrict__ lt,     // [8,32,9]
    const float* __restrict__ lb,     // [8,9]
    float* __restrict__ outp)         // [B*N,256]
{
    __shared__ __align__(16) ushort_t qs_lds[64*32];
    __shared__ __align__(16) ushort_t kp_lds[256*32];
    __shared__ __align__(16) ushort_t vpT_lds[32*264];
    __shared__ __align__(16) ushort_t w_lds[64*264];
    __shared__ float lt_lds[32*12];
    __shared__ float wloc[64*10];
    __shared__ float wext[64*10];
    __shared__ float invs2[64];
    __shared__ float qe_lds[32];
    __shared__ float rpb_lds[9], lb_lds[9];

    const int tile = blockIdx.x;   // 0..63
    const int hh   = blockIdx.y;   // 0..7
    const int b    = blockIdx.z;   // 0..3
    const int tid  = threadIdx.x;
    const int wv   = tid >> 6;     // wave 0..3
    const int lane = tid & 63;
    const int la   = lane & 15;    // col field
    const int lg   = lane >> 4;    // k-chunk / row-group field
    const int r0   = wv * 16;      // wave's first row within the 64-row tile

    // ================= Phase 0: staging =================
    {   // Kp normalize + store (chunk-swizzled); VpT store. thread = pooled pos.
        const float* src = kvp_g + ((size_t)(b * PL_ + tid)) * 512 + hh * D_;
        float kk[32]; float ss = 0.f;
        #pragma unroll
        for (int i = 0; i < 8; ++i) {
            float4 v = *(const float4*)&src[i*4];
            kk[i*4+0]=v.x; kk[i*4+1]=v.y; kk[i*4+2]=v.z; kk[i*4+3]=v.w;
            ss += v.x*v.x + v.y*v.y + v.z*v.z + v.w*v.w;
        }
        float inv = rsqrtf(ss + 1e-12f);
        #pragma unroll
        for (int c = 0; c < 4; ++c) {
            short8b v;
            #pragma unroll
            for (int j = 0; j < 8; ++j) v[j] = (short)f2bf(kk[c*8+j] * inv);
            *(short8b*)&kp_lds[tid*32 + ((c ^ (tid & 3)) * 8)] = v;
        }
        #pragma unroll
        for (int d = 0; d < 32; ++d) vpT_lds[d*264 + tid] = f2bf(src[256 + d]);
    }
    if (tid < 64) {  // q rows -> q_scaled bf16 (swizzled), invs2
        int n = tile*64 + tid;
        const float* src = q_g + ((size_t)(b * N_ + n)) * C_ + hh * D_;
        float qq[32]; float ss = 0.f;
        #pragma unroll
        for (int i = 0; i < 8; ++i) {
            float4 v = *(const float4*)&src[i*4];
            qq[i*4+0]=v.x; qq[i*4+1]=v.y; qq[i*4+2]=v.z; qq[i*4+3]=v.w;
            ss += v.x*v.x + v.y*v.y + v.z*v.z + v.w*v.w;
        }
        float inv = rsqrtf(ss + 1e-12f);
        float sp  = log1pf(expf(temp[hh]));
        int y = n >> 6, x = n & 63;
        int ci = 1 + (y > 0) + (y < IMG-1);
        int cj = 1 + (x > 0) + (x < IMG-1);
        float s2 = sp * logf((float)(ci*cj) + (float)PL_);
        invs2[tid] = 1.0f / s2;
        #pragma unroll
        for (int c = 0; c < 4; ++c) {
            short8b v;
            #pragma unroll
            for (int j = 0; j < 8; ++j) {
                int d = c*8 + j;
                v[j] = (short)f2bf((qq[d]*inv + qe[hh*D_ + d]) * s2);
            }
            *(short8b*)&qs_lds[tid*32 + ((c ^ (tid & 3)) * 8)] = v;
        }
    }
    if (tid < 32) {
        #pragma unroll
        for (int l = 0; l < 9; ++l) lt_lds[tid*12 + l] = lt[hh*288 + tid*9 + l];
        qe_lds[tid] = qe[hh*D_ + tid];
    }
    if (tid < 9) { rpb_lds[tid] = rpb[hh*9 + tid]; lb_lds[tid] = lb[hh*9 + tid]; }
    __syncthreads();

    // ================= Phase 1: local logits + extras (per wave) ==========
    for (int it = 0; it < 3; ++it) {
        int task = lane + 64*it;
        if (task < 144) {
            int r = task / 9;
            int l = task - r*9;
            int rr = r0 + r;
            int n  = tile*64 + rr;
            int y = n >> 6, x = n & 63;
            int yy = y + l/3 - 1, xx = x + (l%3) - 1;
            bool valid = (yy >= 0 && yy < IMG && xx >= 0 && xx < IMG);
            int m = valid ? (yy*IMG + xx) : 0;
            const float* krow = kv_g + ((size_t)(b*N_ + m)) * 512 + hh*D_;
            float is2 = invs2[rr];
            float s1 = 0.f, s22 = 0.f, ee = 0.f;
            #pragma unroll
            for (int i = 0; i < 8; ++i) {
                float4 kv4 = valid ? *(const float4*)&krow[i*4]
                                   : make_float4(0.f,0.f,0.f,0.f);
                float kvv[4] = {kv4.x, kv4.y, kv4.z, kv4.w};
                #pragma unroll
                for (int j = 0; j < 4; ++j) {
                    int d = i*4 + j;
                    float qsv = bf2f(qs_lds[rr*32 + (((d>>3) ^ (rr&3))<<3) + (d&7)]);
                    s1  += qsv * kvv[j];
                    s22 += kvv[j] * kvv[j];
                    float qnv = qsv * is2 - qe_lds[d];
                    ee  += qnv * lt_lds[d*12 + l];
                }
            }
            wloc[rr*10 + l] = valid ? (s1 * rsqrtf(s22 + 1e-12f) + rpb_lds[l]) : -1e9f;
            wext[rr*10 + l] = ee + lb_lds[l];
        }
    }

    // ================= Phase 2: QK^T pool logits (MFMA) ===================
    const int arow = r0 + la;
    const int sw   = (la & 3);  // row/col swizzle key
    short8b af = *(const short8b*)&qs_lds[arow*32 + ((lg ^ sw) * 8)];

    const int nbase = tile*64 + r0 + lg*4;
    const int* rp0 = rpi + (size_t)(nbase+0) * PL_;
    const int* rp1 = rpi + (size_t)(nbase+1) * PL_;
    const int* rp2 = rpi + (size_t)(nbase+2) * PL_;
    const int* rp3 = rpi + (size_t)(nbase+3) * PL_;
    const float* tTh = tT + hh*1024;

    f32x4 acc[16];
    #pragma unroll
    for (int t = 0; t < 16; ++t) {
        int p = t*16 + la;
        f32x4 c;
        c[0] = tTh[rp0[p]];
        c[1] = tTh[rp1[p]];
        c[2] = tTh[rp2[p]];
        c[3] = tTh[rp3[p]];
        short8b bf = *(const short8b*)&kp_lds[p*32 + ((lg ^ sw) * 8)];
        acc[t] = __builtin_amdgcn_mfma_f32_16x16x32_bf16(af, bf, c, 0, 0, 0);
    }

    // ================= Phase 3: joint softmax =============================
    #pragma unroll
    for (int reg = 0; reg < 4; ++reg) {
        int rr = r0 + lg*4 + reg;
        float lval = (la < 9) ? wloc[rr*10 + la] : -3.0e38f;
        float mval = lval;
        #pragma unroll
        for (int t = 0; t < 16; ++t) mval = fmaxf(mval, acc[t][reg]);
        #pragma unroll
        for (int o = 1; o < 16; o <<= 1) mval = fmaxf(mval, __shfl_xor(mval, o, 16));
        float e_l = (la < 9) ? __expf(lval - mval) : 0.f;
        float s = e_l;
        #pragma unroll
        for (int t = 0; t < 16; ++t) {
            float e = __expf(acc[t][reg] - mval);
            acc[t][reg] = e;
            s += e;
        }
        #pragma unroll
        for (int o = 1; o < 16; o <<= 1) s += __shfl_xor(s, o, 16);
        float inv = 1.f / s;
        if (la < 9) wloc[rr*10 + la] = e_l * inv + wext[rr*10 + la];
        #pragma unroll
        for (int t = 0; t < 16; ++t)
            w_lds[rr*264 + t*16 + la] = f2bf(acc[t][reg] * inv);
    }

    // ================= Phase 4: PV ========================================
    f32x4 oacc0 = {0.f,0.f,0.f,0.f}, oacc1 = {0.f,0.f,0.f,0.f};
    #pragma unroll
    for (int kk = 0; kk < 8; ++kk) {
        short8b wf  = *(const short8b*)&w_lds[(r0+la)*264 + kk*32 + lg*8];
        short8b vf0 = *(const short8b*)&vpT_lds[la*264       + kk*32 + lg*8];
        short8b vf1 = *(const short8b*)&vpT_lds[(16+la)*264  + kk*32 + lg*8];
        oacc0 = __builtin_amdgcn_mfma_f32_16x16x32_bf16(wf, vf0, oacc0, 0, 0, 0);
        oacc1 = __builtin_amdgcn_mfma_f32_16x16x32_bf16(wf, vf1, oacc1, 0, 0, 0);
    }
    #pragma unroll
    for (int reg = 0; reg < 4; ++reg) {
        int rr = r0 + lg*4 + reg;
        int n  = tile*64 + rr;
        int y = n >> 6, x = n & 63;
        float o0 = oacc0[reg], o1 = oacc1[reg];
        #pragma unroll
        for (int l = 0; l < 9; ++l) {
            int yy = y + l/3 - 1, xx = x + (l%3) - 1;
            if (yy >= 0 && yy < IMG && xx >= 0 && xx < IMG) {
                float wl = wloc[rr*10 + l];
                const float* vrow = kv_g + ((size_t)(b*N_ + yy*IMG + xx))*512 + 256 + hh*D_;
                o0 += wl * vrow[la];
                o1 += wl * vrow[16 + la];
            }
        }
        float* orow = outp + ((size_t)(b*N_ + n)) * C_ + hh*D_;
        orow[la]      = o0;
        orow[16 + la] = o1;
    }
}

// ---------------------------------------------------------------------------
extern "C" void kernel_launch(void* const* d_in, const int* in_sizes, int n_in,
                              void* d_out, int out_size, void* d_ws, size_t ws_size,
                              hipStream_t stream) {
    const float* x    = (const float*)d_in[0];
    const float* rct  = (const float*)d_in[1];
    const int*   rpi  = (const int*)  d_in[2];
    const float* q_w  = (const float*)d_in[3];
    const float* q_b  = (const float*)d_in[4];
    const float* kv_w = (const float*)d_in[5];
    const float* kv_b = (const float*)d_in[6];
    const float* temp = (const float*)d_in[7];
    const float* qe   = (const float*)d_in[8];
    const float* sr_w = (const float*)d_in[9];
    const float* sr_b = (const float*)d_in[10];
    const float* ng   = (const float*)d_in[11];
    const float* nb   = (const float*)d_in[12];
    const float* c1w  = (const float*)d_in[13];
    const float* c1b  = (const float*)d_in[14];
    const float* c2w  = (const float*)d_in[15];
    const float* c2b  = (const float*)d_in[16];
    const float* rpb  = (const float*)d_in[17];
    const float* lt   = (const float*)d_in[18];
    const float* lb   = (const float*)d_in[19];
    const float* p_w  = (const float*)d_in[20];
    const float* p_b  = (const float*)d_in[21];
    float* out = (float*)d_out;

    float* ws = (float*)d_ws;
    const size_t MN = (size_t)B_ * N_;               // 16384
    float* buf_q   = ws;                             // [MN,256] raw q
    float* buf_kv  = buf_q   + MN * 256;             // [MN,512] raw k|v
    float* buf_sr  = buf_kv  + MN * 512;             // [MN,256] gelu(sr); later attn out
    float* buf_xs  = buf_sr  + MN * 256;             // [B*PL,256]
    float* buf_kvp = buf_xs  + (size_t)B_*PL_*256;   // [B*PL,512] raw k|v pooled
    float* buf_t   = buf_kvp + (size_t)B_*PL_*512;   // [8,1024]
    float* buf_pre = buf_sr;

    const int M = (int)MN;  // 16384

    gemm128<0><<<dim3(2, M/128), 256, 0, stream>>>(x, q_w,  q_b,  buf_q,  M, 256, 256);
    gemm128<0><<<dim3(4, M/128), 256, 0, stream>>>(x, kv_w, kv_b, buf_kv, M, 512, 256);
    gemm128<1><<<dim3(2, M/128), 256, 0, stream>>>(x, sr_w, sr_b, buf_sr, M, 256, 256);

    pool_ln_kernel<<<B_ * PL_, 256, 0, stream>>>(buf_sr, ng, nb, buf_xs);
    gemm128<0><<<dim3(4, (B_*PL_)/128), 256, 0, stream>>>(buf_xs, kv_w, kv_b, buf_kvp,
                                                          B_*PL_, 512, 256);
    cpb_kernel<<<1024, 64, 0, stream>>>(rct, c1w, c1b, c2w, c2b, buf_t);

    attn_mfma<<<dim3(64, 8, 4), 256, 0, stream>>>(buf_q, buf_kv, buf_kvp, buf_t,
                                                  rpi, rpb, qe, temp, lt, lb, buf_pre);

    gemm128<0><<<dim3(2, M/128), 256, 0, stream>>>(buf_pre, p_w, p_b, out, M, 256, 256);
}

// Round 4
// 272.816 us; speedup vs baseline: 8.2798x; 1.3671x over previous
//
#include <hip/hip_runtime.h>
#include <math.h>

#define B_   4
#define N_   4096
#define C_   256
#define NH   8      // heads
#define D_   32     // head dim
#define PL_  256    // pooled length
#define IMG  64     // H = W = 64

typedef __attribute__((ext_vector_type(8))) short short8b;
typedef __attribute__((ext_vector_type(4))) float f32x4;
typedef unsigned short ushort_t;

__device__ __forceinline__ ushort_t f2bf(float f) {
    unsigned u = __float_as_uint(f);
    u += 0x7FFFu + ((u >> 16) & 1u);   // RTNE
    return (ushort_t)(u >> 16);
}
__device__ __forceinline__ float bf2f(ushort_t s) {
    return __uint_as_float(((unsigned)s) << 16);
}

__device__ __forceinline__ float gelu_f(float v) {
    return 0.5f * v * (1.0f + erff(v * 0.70710678118654752440f));
}

// ---------------------------------------------------------------------------
// f32 -> bf16 bulk convert (8 elems/thread)
// ---------------------------------------------------------------------------
__global__ __launch_bounds__(256) void tobf16_kernel(const float* __restrict__ in,
                                                     ushort_t* __restrict__ out,
                                                     int n8)
{
    int i = blockIdx.x * 256 + threadIdx.x;
    if (i >= n8) return;
    const float4* p = (const float4*)(in + (size_t)i * 8);
    float4 v0 = p[0], v1 = p[1];
    short8b o;
    o[0] = (short)f2bf(v0.x); o[1] = (short)f2bf(v0.y);
    o[2] = (short)f2bf(v0.z); o[3] = (short)f2bf(v0.w);
    o[4] = (short)f2bf(v1.x); o[5] = (short)f2bf(v1.y);
    o[6] = (short)f2bf(v1.z); o[7] = (short)f2bf(v1.w);
    *(short8b*)&out[(size_t)i * 8] = o;
}

// ---------------------------------------------------------------------------
// Weight transpose+convert: W[K][N] f32 -> WT[N][K] bf16
// ---------------------------------------------------------------------------
__global__ __launch_bounds__(256) void wtrans_kernel(const float* __restrict__ W,
                                                     ushort_t* __restrict__ WT,
                                                     int K, int N)
{
    int gid = blockIdx.x * 256 + threadIdx.x;
    int per_row = K >> 3;
    int n = gid / per_row;
    if (n >= N) return;
    int k0 = (gid - n * per_row) << 3;
    short8b v;
    #pragma unroll
    for (int j = 0; j < 8; ++j) v[j] = (short)f2bf(W[(size_t)(k0 + j) * N + n]);
    *(short8b*)&WT[(size_t)n * K + k0] = v;
}

// ---------------------------------------------------------------------------
// bf16 MFMA GEMM: out[M,N] = Abf[M,K] @ WT[N,K]^T + bias, ACT=1 -> GELU.
// No LDS: fragments read straight from global (WT is L1/L2-resident).
// 256 threads = 4 waves; block tile 128x64; wave tile 32x64.
// Fragment layout verified in attn_mfma (round 3).
// ---------------------------------------------------------------------------
template<int ACT>
__global__ __launch_bounds__(256) void gemm_mfma(const ushort_t* __restrict__ Abf,
                                                 const ushort_t* __restrict__ WT,
                                                 const float* __restrict__ bias,
                                                 float* __restrict__ out,
                                                 int M, int N, int K)
{
    const int tid  = threadIdx.x;
    const int wv   = tid >> 6;
    const int lane = tid & 63;
    const int la   = lane & 15, lg = lane >> 4;
    const int m0   = blockIdx.y * 128 + wv * 32;
    const int n0   = blockIdx.x * 64;

    const ushort_t* a0p = Abf + (size_t)(m0 + la) * K + lg * 8;
    const ushort_t* a1p = a0p + (size_t)16 * K;
    const ushort_t* b0p = WT + (size_t)(n0 + la) * K + lg * 8;

    f32x4 acc[2][4];
    #pragma unroll
    for (int i = 0; i < 2; ++i)
        #pragma unroll
        for (int j = 0; j < 4; ++j) acc[i][j] = (f32x4){0.f, 0.f, 0.f, 0.f};

    for (int k = 0; k < K; k += 32) {
        short8b a0 = *(const short8b*)(a0p + k);
        short8b a1 = *(const short8b*)(a1p + k);
        #pragma unroll
        for (int nf = 0; nf < 4; ++nf) {
            short8b bb = *(const short8b*)(b0p + (size_t)nf * 16 * K + k);
            acc[0][nf] = __builtin_amdgcn_mfma_f32_16x16x32_bf16(a0, bb, acc[0][nf], 0, 0, 0);
            acc[1][nf] = __builtin_amdgcn_mfma_f32_16x16x32_bf16(a1, bb, acc[1][nf], 0, 0, 0);
        }
    }
    #pragma unroll
    for (int mf = 0; mf < 2; ++mf)
        #pragma unroll
        for (int nf = 0; nf < 4; ++nf)
            #pragma unroll
            for (int reg = 0; reg < 4; ++reg) {
                int m  = m0 + mf * 16 + lg * 4 + reg;
                int nn = n0 + nf * 16 + la;
                float v = acc[mf][nf][reg] + bias[nn];
                if (ACT == 1) v = gelu_f(v);
                out[(size_t)m * N + nn] = v;
            }
}

// ---------------------------------------------------------------------------
// Generic fp32 tiled GEMM (validated): used only for the small kvp GEMM.
// ---------------------------------------------------------------------------
template<int ACT>
__global__ __launch_bounds__(256) void gemm128(const float* __restrict__ A,
                                               const float* __restrict__ W,
                                               const float* __restrict__ bias,
                                               float* __restrict__ out,
                                               int M, int N, int K)
{
    __shared__ float As[8][132];
    __shared__ float Bs[8][128];
    const int t  = threadIdx.x;
    const int tx = t & 15, ty = t >> 4;
    const int m0 = blockIdx.y * 128, n0 = blockIdx.x * 128;

    float acc[8][8];
    #pragma unroll
    for (int i = 0; i < 8; ++i)
        #pragma unroll
        for (int j = 0; j < 8; ++j) acc[i][j] = 0.f;

    const int arow = t >> 1, akq = t & 1;
    const int brow = t >> 5, bq  = t & 31;
    for (int k0 = 0; k0 < K; k0 += 8) {
        float4 a4 = *(const float4*)&A[(size_t)(m0 + arow) * K + k0 + akq * 4];
        As[akq*4+0][arow] = a4.x;
        As[akq*4+1][arow] = a4.y;
        As[akq*4+2][arow] = a4.z;
        As[akq*4+3][arow] = a4.w;
        *(float4*)&Bs[brow][bq*4] =
            *(const float4*)&W[(size_t)(k0 + brow) * N + n0 + bq*4];
        __syncthreads();
        #pragma unroll
        for (int kk = 0; kk < 8; ++kk) {
            float4 a0 = *(const float4*)&As[kk][ty*8];
            float4 a1 = *(const float4*)&As[kk][ty*8+4];
            float4 b0 = *(const float4*)&Bs[kk][tx*8];
            float4 b1 = *(const float4*)&Bs[kk][tx*8+4];
            float av[8] = {a0.x,a0.y,a0.z,a0.w,a1.x,a1.y,a1.z,a1.w};
            float bv[8] = {b0.x,b0.y,b0.z,b0.w,b1.x,b1.y,b1.z,b1.w};
            #pragma unroll
            for (int i = 0; i < 8; ++i)
                #pragma unroll
                for (int j = 0; j < 8; ++j)
                    acc[i][j] = fmaf(av[i], bv[j], acc[i][j]);
        }
        __syncthreads();
    }
    #pragma unroll
    for (int i = 0; i < 8; ++i) {
        int m = m0 + ty*8 + i;
        #pragma unroll
        for (int j0 = 0; j0 < 8; j0 += 4) {
            int n = n0 + tx*8 + j0;
            float4 r;
            r.x = acc[i][j0+0] + bias[n+0];
            r.y = acc[i][j0+1] + bias[n+1];
            r.z = acc[i][j0+2] + bias[n+2];
            r.w = acc[i][j0+3] + bias[n+3];
            if (ACT == 1) {
                r.x = gelu_f(r.x); r.y = gelu_f(r.y);
                r.z = gelu_f(r.z); r.w = gelu_f(r.w);
            }
            *(float4*)&out[(size_t)m * N + n] = r;
        }
    }
}

// ---------------------------------------------------------------------------
// pool_ln (validated)
// ---------------------------------------------------------------------------
__global__ __launch_bounds__(256) void pool_ln_kernel(const float* __restrict__ sr,
                                                      const float* __restrict__ g,
                                                      const float* __restrict__ bb,
                                                      float* __restrict__ xs)
{
    __shared__ float red[256];
    int bp = blockIdx.x;
    int b = bp >> 8, p = bp & 255;
    int i0 = p >> 4, j0 = p & 15;
    int c = threadIdx.x;
    float s = 0.f;
    #pragma unroll
    for (int di = 0; di < 4; ++di)
        #pragma unroll
        for (int dj = 0; dj < 4; ++dj) {
            int n = (i0*4 + di) * IMG + (j0*4 + dj);
            s += sr[((size_t)b * N_ + n) * C_ + c];
        }
    s *= (1.f / 16.f);
    red[c] = s; __syncthreads();
    for (int o = 128; o > 0; o >>= 1) { if (c < o) red[c] += red[c+o]; __syncthreads(); }
    float mean = red[0] * (1.f/256.f);
    __syncthreads();
    float dcen = s - mean;
    red[c] = dcen * dcen; __syncthreads();
    for (int o = 128; o > 0; o >>= 1) { if (c < o) red[c] += red[c+o]; __syncthreads(); }
    float var = red[0] * (1.f/256.f);
    float outv = dcen * rsqrtf(var + 1e-5f) * g[c] + bb[c];
    xs[(size_t)bp * C_ + c] = outv;
}

// ---------------------------------------------------------------------------
// cpb (validated): tT[h][1024]
// ---------------------------------------------------------------------------
__global__ __launch_bounds__(64) void cpb_kernel(const float* __restrict__ rct,
                                                 const float* __restrict__ w1,
                                                 const float* __restrict__ b1,
                                                 const float* __restrict__ w2,
                                                 const float* __restrict__ b2,
                                                 float* __restrict__ tT)
{
    int l = blockIdx.x;
    int lane = threadIdx.x;
    float c0 = rct[l*2+0], c1 = rct[l*2+1];
    float acc[8] = {0,0,0,0,0,0,0,0};
    for (int j = lane; j < 512; j += 64) {
        float hv = fmaxf(c0 * w1[j] + c1 * w1[512+j] + b1[j], 0.f);
        #pragma unroll
        for (int hh = 0; hh < 8; ++hh) acc[hh] += hv * w2[j*8 + hh];
    }
    #pragma unroll
    for (int o = 32; o > 0; o >>= 1)
        #pragma unroll
        for (int hh = 0; hh < 8; ++hh) acc[hh] += __shfl_xor(acc[hh], o, 64);
    if (lane < 8) tT[lane * 1024 + l] = acc[lane] + b2[lane];
}

// ---------------------------------------------------------------------------
// attn_mfma (validated round 3, output now bf16 for the proj GEMM)
// ---------------------------------------------------------------------------
__global__ __launch_bounds__(256, 2) void attn_mfma(
    const float* __restrict__ q_g,    // raw q  [B*N,256]
    const float* __restrict__ kv_g,   // raw kv [B*N,512]
    const float* __restrict__ kvp_g,  // raw kvp[B*PL,512]
    const float* __restrict__ tT,     // [8,1024]
    const int*   __restrict__ rpi,    // [N,PL]
    const float* __restrict__ rpb,    // [8,9]
    const float* __restrict__ qe,     // [8,32]
    const float* __restrict__ temp,   // [8]
    const float* __restrict__ lt,     // [8,32,9]
    const float* __restrict__ lb,     // [8,9]
    ushort_t* __restrict__ outp)      // bf16 [B*N,256]
{
    __shared__ __align__(16) ushort_t qs_lds[64*32];
    __shared__ __align__(16) ushort_t kp_lds[256*32];
    __shared__ __align__(16) ushort_t vpT_lds[32*264];
    __shared__ __align__(16) ushort_t w_lds[64*264];
    __shared__ float lt_lds[32*12];
    __shared__ float wloc[64*10];
    __shared__ float wext[64*10];
    __shared__ float invs2[64];
    __shared__ float qe_lds[32];
    __shared__ float rpb_lds[9], lb_lds[9];

    const int tile = blockIdx.x;   // 0..63
    const int hh   = blockIdx.y;   // 0..7
    const int b    = blockIdx.z;   // 0..3
    const int tid  = threadIdx.x;
    const int wv   = tid >> 6;     // wave 0..3
    const int lane = tid & 63;
    const int la   = lane & 15;    // col field
    const int lg   = lane >> 4;    // k-chunk / row-group field
    const int r0   = wv * 16;      // wave's first row within the 64-row tile

    // ================= Phase 0: staging =================
    {   // Kp normalize + store (chunk-swizzled); VpT store. thread = pooled pos.
        const float* src = kvp_g + ((size_t)(b * PL_ + tid)) * 512 + hh * D_;
        float kk[32]; float ss = 0.f;
        #pragma unroll
        for (int i = 0; i < 8; ++i) {
            float4 v = *(const float4*)&src[i*4];
            kk[i*4+0]=v.x; kk[i*4+1]=v.y; kk[i*4+2]=v.z; kk[i*4+3]=v.w;
            ss += v.x*v.x + v.y*v.y + v.z*v.z + v.w*v.w;
        }
        float inv = rsqrtf(ss + 1e-12f);
        #pragma unroll
        for (int c = 0; c < 4; ++c) {
            short8b v;
            #pragma unroll
            for (int j = 0; j < 8; ++j) v[j] = (short)f2bf(kk[c*8+j] * inv);
            *(short8b*)&kp_lds[tid*32 + ((c ^ (tid & 3)) * 8)] = v;
        }
        #pragma unroll
        for (int d = 0; d < 32; ++d) vpT_lds[d*264 + tid] = f2bf(src[256 + d]);
    }
    if (tid < 64) {  // q rows -> q_scaled bf16 (swizzled), invs2
        int n = tile*64 + tid;
        const float* src = q_g + ((size_t)(b * N_ + n)) * C_ + hh * D_;
        float qq[32]; float ss = 0.f;
        #pragma unroll
        for (int i = 0; i < 8; ++i) {
            float4 v = *(const float4*)&src[i*4];
            qq[i*4+0]=v.x; qq[i*4+1]=v.y; qq[i*4+2]=v.z; qq[i*4+3]=v.w;
            ss += v.x*v.x + v.y*v.y + v.z*v.z + v.w*v.w;
        }
        float inv = rsqrtf(ss + 1e-12f);
        float sp  = log1pf(expf(temp[hh]));
        int y = n >> 6, x = n & 63;
        int ci = 1 + (y > 0) + (y < IMG-1);
        int cj = 1 + (x > 0) + (x < IMG-1);
        float s2 = sp * logf((float)(ci*cj) + (float)PL_);
        invs2[tid] = 1.0f / s2;
        #pragma unroll
        for (int c = 0; c < 4; ++c) {
            short8b v;
            #pragma unroll
            for (int j = 0; j < 8; ++j) {
                int d = c*8 + j;
                v[j] = (short)f2bf((qq[d]*inv + qe[hh*D_ + d]) * s2);
            }
            *(short8b*)&qs_lds[tid*32 + ((c ^ (tid & 3)) * 8)] = v;
        }
    }
    if (tid < 32) {
        #pragma unroll
        for (int l = 0; l < 9; ++l) lt_lds[tid*12 + l] = lt[hh*288 + tid*9 + l];
        qe_lds[tid] = qe[hh*D_ + tid];
    }
    if (tid < 9) { rpb_lds[tid] = rpb[hh*9 + tid]; lb_lds[tid] = lb[hh*9 + tid]; }
    __syncthreads();

    // ================= Phase 1: local logits + extras (per wave) ==========
    for (int it = 0; it < 3; ++it) {
        int task = lane + 64*it;
        if (task < 144) {
            int r = task / 9;
            int l = task - r*9;
            int rr = r0 + r;
            int n  = tile*64 + rr;
            int y = n >> 6, x = n & 63;
            int yy = y + l/3 - 1, xx = x + (l%3) - 1;
            bool valid = (yy >= 0 && yy < IMG && xx >= 0 && xx < IMG);
            int m = valid ? (yy*IMG + xx) : 0;
            const float* krow = kv_g + ((size_t)(b*N_ + m)) * 512 + hh*D_;
            float is2 = invs2[rr];
            float s1 = 0.f, s22 = 0.f, ee = 0.f;
            #pragma unroll
            for (int i = 0; i < 8; ++i) {
                float4 kv4 = valid ? *(const float4*)&krow[i*4]
                                   : make_float4(0.f,0.f,0.f,0.f);
                float kvv[4] = {kv4.x, kv4.y, kv4.z, kv4.w};
                #pragma unroll
                for (int j = 0; j < 4; ++j) {
                    int d = i*4 + j;
                    float qsv = bf2f(qs_lds[rr*32 + (((d>>3) ^ (rr&3))<<3) + (d&7)]);
                    s1  += qsv * kvv[j];
                    s22 += kvv[j] * kvv[j];
                    float qnv = qsv * is2 - qe_lds[d];
                    ee  += qnv * lt_lds[d*12 + l];
                }
            }
            wloc[rr*10 + l] = valid ? (s1 * rsqrtf(s22 + 1e-12f) + rpb_lds[l]) : -1e9f;
            wext[rr*10 + l] = ee + lb_lds[l];
        }
    }

    // ================= Phase 2: QK^T pool logits (MFMA) ===================
    const int arow = r0 + la;
    const int sw   = (la & 3);  // row/col swizzle key
    short8b af = *(const short8b*)&qs_lds[arow*32 + ((lg ^ sw) * 8)];

    const int nbase = tile*64 + r0 + lg*4;
    const int* rp0 = rpi + (size_t)(nbase+0) * PL_;
    const int* rp1 = rpi + (size_t)(nbase+1) * PL_;
    const int* rp2 = rpi + (size_t)(nbase+2) * PL_;
    const int* rp3 = rpi + (size_t)(nbase+3) * PL_;
    const float* tTh = tT + hh*1024;

    f32x4 acc[16];
    #pragma unroll
    for (int t = 0; t < 16; ++t) {
        int p = t*16 + la;
        f32x4 c;
        c[0] = tTh[rp0[p]];
        c[1] = tTh[rp1[p]];
        c[2] = tTh[rp2[p]];
        c[3] = tTh[rp3[p]];
        short8b bf = *(const short8b*)&kp_lds[p*32 + ((lg ^ sw) * 8)];
        acc[t] = __builtin_amdgcn_mfma_f32_16x16x32_bf16(af, bf, c, 0, 0, 0);
    }

    // ================= Phase 3: joint softmax =============================
    #pragma unroll
    for (int reg = 0; reg < 4; ++reg) {
        int rr = r0 + lg*4 + reg;
        float lval = (la < 9) ? wloc[rr*10 + la] : -3.0e38f;
        float mval = lval;
        #pragma unroll
        for (int t = 0; t < 16; ++t) mval = fmaxf(mval, acc[t][reg]);
        #pragma unroll
        for (int o = 1; o < 16; o <<= 1) mval = fmaxf(mval, __shfl_xor(mval, o, 16));
        float e_l = (la < 9) ? __expf(lval - mval) : 0.f;
        float s = e_l;
        #pragma unroll
        for (int t = 0; t < 16; ++t) {
            float e = __expf(acc[t][reg] - mval);
            acc[t][reg] = e;
            s += e;
        }
        #pragma unroll
        for (int o = 1; o < 16; o <<= 1) s += __shfl_xor(s, o, 16);
        float inv = 1.f / s;
        if (la < 9) wloc[rr*10 + la] = e_l * inv + wext[rr*10 + la];
        #pragma unroll
        for (int t = 0; t < 16; ++t)
            w_lds[rr*264 + t*16 + la] = f2bf(acc[t][reg] * inv);
    }

    // ================= Phase 4: PV ========================================
    f32x4 oacc0 = {0.f,0.f,0.f,0.f}, oacc1 = {0.f,0.f,0.f,0.f};
    #pragma unroll
    for (int kk = 0; kk < 8; ++kk) {
        short8b wf  = *(const short8b*)&w_lds[(r0+la)*264 + kk*32 + lg*8];
        short8b vf0 = *(const short8b*)&vpT_lds[la*264       + kk*32 + lg*8];
        short8b vf1 = *(const short8b*)&vpT_lds[(16+la)*264  + kk*32 + lg*8];
        oacc0 = __builtin_amdgcn_mfma_f32_16x16x32_bf16(wf, vf0, oacc0, 0, 0, 0);
        oacc1 = __builtin_amdgcn_mfma_f32_16x16x32_bf16(wf, vf1, oacc1, 0, 0, 0);
    }
    #pragma unroll
    for (int reg = 0; reg < 4; ++reg) {
        int rr = r0 + lg*4 + reg;
        int n  = tile*64 + rr;
        int y = n >> 6, x = n & 63;
        float o0 = oacc0[reg], o1 = oacc1[reg];
        #pragma unroll
        for (int l = 0; l < 9; ++l) {
            int yy = y + l/3 - 1, xx = x + (l%3) - 1;
            if (yy >= 0 && yy < IMG && xx >= 0 && xx < IMG) {
                float wl = wloc[rr*10 + l];
                const float* vrow = kv_g + ((size_t)(b*N_ + yy*IMG + xx))*512 + 256 + hh*D_;
                o0 += wl * vrow[la];
                o1 += wl * vrow[16 + la];
            }
        }
        ushort_t* orow = outp + ((size_t)(b*N_ + n)) * C_ + hh*D_;
        orow[la]      = f2bf(o0);
        orow[16 + la] = f2bf(o1);
    }
}

// ---------------------------------------------------------------------------
extern "C" void kernel_launch(void* const* d_in, const int* in_sizes, int n_in,
                              void* d_out, int out_size, void* d_ws, size_t ws_size,
                              hipStream_t stream) {
    const float* x    = (const float*)d_in[0];
    const float* rct  = (const float*)d_in[1];
    const int*   rpi  = (const int*)  d_in[2];
    const float* q_w  = (const float*)d_in[3];
    const float* q_b  = (const float*)d_in[4];
    const float* kv_w = (const float*)d_in[5];
    const float* kv_b = (const float*)d_in[6];
    const float* temp = (const float*)d_in[7];
    const float* qe   = (const float*)d_in[8];
    const float* sr_w = (const float*)d_in[9];
    const float* sr_b = (const float*)d_in[10];
    const float* ng   = (const float*)d_in[11];
    const float* nb   = (const float*)d_in[12];
    const float* c1w  = (const float*)d_in[13];
    const float* c1b  = (const float*)d_in[14];
    const float* c2w  = (const float*)d_in[15];
    const float* c2b  = (const float*)d_in[16];
    const float* rpb  = (const float*)d_in[17];
    const float* lt   = (const float*)d_in[18];
    const float* lb   = (const float*)d_in[19];
    const float* p_w  = (const float*)d_in[20];
    const float* p_b  = (const float*)d_in[21];
    float* out = (float*)d_out;

    float* ws = (float*)d_ws;
    const size_t MN = (size_t)B_ * N_;               // 16384
    float* buf_q   = ws;                             // [MN,256] raw q f32
    float* buf_kv  = buf_q   + MN * 256;             // [MN,512] raw k|v f32
    float* buf_sr  = buf_kv  + MN * 512;             // [MN,256] gelu(sr) f32
    float* buf_xs  = buf_sr  + MN * 256;             // [B*PL,256]
    float* buf_kvp = buf_xs  + (size_t)B_*PL_*256;   // [B*PL,512]
    float* buf_t   = buf_kvp + (size_t)B_*PL_*512;   // [8,1024]
    ushort_t* bf_base = (ushort_t*)(buf_t + 8*1024);
    ushort_t* x_bf   = bf_base;                      // [MN,256] bf16
    ushort_t* pre_bf = x_bf   + MN * 256;            // [MN,256] bf16 attn out
    ushort_t* qwT    = pre_bf + MN * 256;            // [256,256]
    ushort_t* kvwT   = qwT    + 256*256;             // [512,256]
    ushort_t* srwT   = kvwT   + 512*256;             // [256,256]
    ushort_t* pwT    = srwT   + 256*256;             // [256,256]

    const int M = (int)MN;  // 16384

    // conversions
    tobf16_kernel<<<(M*256/8 + 255)/256, 256, 0, stream>>>(x, x_bf, M*256/8);
    wtrans_kernel<<<(256*256/8 + 255)/256, 256, 0, stream>>>(q_w,  qwT,  256, 256);
    wtrans_kernel<<<(512*256/8 + 255)/256, 256, 0, stream>>>(kv_w, kvwT, 256, 512);
    wtrans_kernel<<<(256*256/8 + 255)/256, 256, 0, stream>>>(sr_w, srwT, 256, 256);
    wtrans_kernel<<<(256*256/8 + 255)/256, 256, 0, stream>>>(p_w,  pwT,  256, 256);

    // big GEMMs on MFMA
    gemm_mfma<0><<<dim3(256/64, M/128), 256, 0, stream>>>(x_bf, qwT,  q_b,  buf_q,  M, 256, 256);
    gemm_mfma<0><<<dim3(512/64, M/128), 256, 0, stream>>>(x_bf, kvwT, kv_b, buf_kv, M, 512, 256);
    gemm_mfma<1><<<dim3(256/64, M/128), 256, 0, stream>>>(x_bf, srwT, sr_b, buf_sr, M, 256, 256);

    pool_ln_kernel<<<B_ * PL_, 256, 0, stream>>>(buf_sr, ng, nb, buf_xs);
    gemm128<0><<<dim3(4, (B_*PL_)/128), 256, 0, stream>>>(buf_xs, kv_w, kv_b, buf_kvp,
                                                          B_*PL_, 512, 256);
    cpb_kernel<<<1024, 64, 0, stream>>>(rct, c1w, c1b, c2w, c2b, buf_t);

    attn_mfma<<<dim3(64, 8, 4), 256, 0, stream>>>(buf_q, buf_kv, buf_kvp, buf_t,
                                                  rpi, rpb, qe, temp, lt, lb, pre_bf);

    gemm_mfma<0><<<dim3(256/64, M/128), 256, 0, stream>>>(pre_bf, pwT, p_b, out, M, 256, 256);
}

// Round 5
// 182.344 us; speedup vs baseline: 12.3879x; 1.4962x over previous
//
#include <hip/hip_runtime.h>
#include <math.h>

#define B_   4
#define N_   4096
#define C_   256
#define NH   8      // heads
#define D_   32     // head dim
#define PL_  256    // pooled length
#define IMG  64     // H = W = 64

typedef __attribute__((ext_vector_type(8))) short short8b;
typedef __attribute__((ext_vector_type(4))) float f32x4;
typedef unsigned short ushort_t;

__device__ __forceinline__ ushort_t f2bf(float f) {
    unsigned u = __float_as_uint(f);
    u += 0x7FFFu + ((u >> 16) & 1u);   // RTNE
    return (ushort_t)(u >> 16);
}
__device__ __forceinline__ float bf2f(ushort_t s) {
    return __uint_as_float(((unsigned)s) << 16);
}
__device__ __forceinline__ unsigned pk2(float lo, float hi) {
    return (unsigned)f2bf(lo) | ((unsigned)f2bf(hi) << 16);
}

__device__ __forceinline__ float gelu_f(float v) {
    return 0.5f * v * (1.0f + erff(v * 0.70710678118654752440f));
}

// ---------------------------------------------------------------------------
// f32 -> bf16 bulk convert (8 elems/thread)
// ---------------------------------------------------------------------------
__global__ __launch_bounds__(256) void tobf16_kernel(const float* __restrict__ in,
                                                     ushort_t* __restrict__ out,
                                                     int n8)
{
    int i = blockIdx.x * 256 + threadIdx.x;
    if (i >= n8) return;
    const float4* p = (const float4*)(in + (size_t)i * 8);
    float4 v0 = p[0], v1 = p[1];
    short8b o;
    o[0] = (short)f2bf(v0.x); o[1] = (short)f2bf(v0.y);
    o[2] = (short)f2bf(v0.z); o[3] = (short)f2bf(v0.w);
    o[4] = (short)f2bf(v1.x); o[5] = (short)f2bf(v1.y);
    o[6] = (short)f2bf(v1.z); o[7] = (short)f2bf(v1.w);
    *(short8b*)&out[(size_t)i * 8] = o;
}

// ---------------------------------------------------------------------------
// Weight transpose+convert: W[K][N] f32 -> WT[N][K] bf16  (K=256 here)
// ---------------------------------------------------------------------------
__global__ __launch_bounds__(256) void wtrans_kernel(const float* __restrict__ W,
                                                     ushort_t* __restrict__ WT,
                                                     int K, int N)
{
    int gid = blockIdx.x * 256 + threadIdx.x;
    int per_row = K >> 3;
    int n = gid / per_row;
    if (n >= N) return;
    int k0 = (gid - n * per_row) << 3;
    short8b v;
    #pragma unroll
    for (int j = 0; j < 8; ++j) v[j] = (short)f2bf(W[(size_t)(k0 + j) * N + n]);
    *(short8b*)&WT[(size_t)n * K + k0] = v;
}

// ---------------------------------------------------------------------------
// bf16 MFMA GEMM, K=256: out[M,N] = Abf @ WT^T + bias, ACT=1 -> GELU.
// B tile (64 cols x 256 k = 32KB) staged in LDS with chunk-XOR swizzle.
// 256 threads = 4 waves; block tile 128x64; wave tile 32x64.
// ---------------------------------------------------------------------------
template<int ACT>
__global__ __launch_bounds__(256) void gemm_mfma(const ushort_t* __restrict__ Abf,
                                                 const ushort_t* __restrict__ WT,
                                                 const float* __restrict__ bias,
                                                 float* __restrict__ out,
                                                 int M, int N)
{
    __shared__ __align__(16) ushort_t Bs[64 * 256];   // 32 KB

    const int tid  = threadIdx.x;
    const int wv   = tid >> 6;
    const int lane = tid & 63;
    const int la   = lane & 15, lg = lane >> 4;
    const int m0   = blockIdx.y * 128 + wv * 32;
    const int n0   = blockIdx.x * 64;

    // stage WT[n0..n0+63][0..255] -> Bs with per-row chunk XOR (key row&3)
    {
        const int srow = tid >> 2, sm = tid & 3;
        const ushort_t* wrow = WT + (size_t)(n0 + srow) * 256;
        #pragma unroll
        for (int c8 = 0; c8 < 8; ++c8) {
            int ck = c8 * 4 + sm;
            short8b v = *(const short8b*)&wrow[ck * 8];
            *(short8b*)&Bs[srow * 256 + ((ck ^ (srow & 3)) * 8)] = v;
        }
    }
    __syncthreads();

    const ushort_t* a0p = Abf + (size_t)(m0 + la) * 256 + lg * 8;
    const ushort_t* a1p = a0p + (size_t)16 * 256;

    f32x4 acc[2][4];
    #pragma unroll
    for (int i = 0; i < 2; ++i)
        #pragma unroll
        for (int j = 0; j < 4; ++j) acc[i][j] = (f32x4){0.f, 0.f, 0.f, 0.f};

    #pragma unroll
    for (int kit = 0; kit < 8; ++kit) {
        short8b a0 = *(const short8b*)(a0p + kit * 32);
        short8b a1 = *(const short8b*)(a1p + kit * 32);
        #pragma unroll
        for (int nf = 0; nf < 4; ++nf) {
            int brow = nf * 16 + la;
            short8b bb = *(const short8b*)&Bs[brow * 256 + (((kit*4 + lg) ^ (la & 3)) * 8)];
            acc[0][nf] = __builtin_amdgcn_mfma_f32_16x16x32_bf16(a0, bb, acc[0][nf], 0, 0, 0);
            acc[1][nf] = __builtin_amdgcn_mfma_f32_16x16x32_bf16(a1, bb, acc[1][nf], 0, 0, 0);
        }
    }
    #pragma unroll
    for (int mf = 0; mf < 2; ++mf)
        #pragma unroll
        for (int nf = 0; nf < 4; ++nf)
            #pragma unroll
            for (int reg = 0; reg < 4; ++reg) {
                int m  = m0 + mf * 16 + lg * 4 + reg;
                int nn = n0 + nf * 16 + la;
                float v = acc[mf][nf][reg] + bias[nn];
                if (ACT == 1) v = gelu_f(v);
                out[(size_t)m * N + nn] = v;
            }
}

// ---------------------------------------------------------------------------
// pool_ln: 4x4 mean-pool of gelu'd sr + LayerNorm -> xs bf16 [B*PL, C]
// ---------------------------------------------------------------------------
__global__ __launch_bounds__(256) void pool_ln_kernel(const float* __restrict__ sr,
                                                      const float* __restrict__ g,
                                                      const float* __restrict__ bb,
                                                      ushort_t* __restrict__ xs)
{
    __shared__ float red[256];
    int bp = blockIdx.x;
    int b = bp >> 8, p = bp & 255;
    int i0 = p >> 4, j0 = p & 15;
    int c = threadIdx.x;
    float s = 0.f;
    #pragma unroll
    for (int di = 0; di < 4; ++di)
        #pragma unroll
        for (int dj = 0; dj < 4; ++dj) {
            int n = (i0*4 + di) * IMG + (j0*4 + dj);
            s += sr[((size_t)b * N_ + n) * C_ + c];
        }
    s *= (1.f / 16.f);
    red[c] = s; __syncthreads();
    for (int o = 128; o > 0; o >>= 1) { if (c < o) red[c] += red[c+o]; __syncthreads(); }
    float mean = red[0] * (1.f/256.f);
    __syncthreads();
    float dcen = s - mean;
    red[c] = dcen * dcen; __syncthreads();
    for (int o = 128; o > 0; o >>= 1) { if (c < o) red[c] += red[c+o]; __syncthreads(); }
    float var = red[0] * (1.f/256.f);
    float outv = dcen * rsqrtf(var + 1e-5f) * g[c] + bb[c];
    xs[(size_t)bp * C_ + c] = f2bf(outv);
}

// ---------------------------------------------------------------------------
// cpb (validated): tT[h][1024]
// ---------------------------------------------------------------------------
__global__ __launch_bounds__(64) void cpb_kernel(const float* __restrict__ rct,
                                                 const float* __restrict__ w1,
                                                 const float* __restrict__ b1,
                                                 const float* __restrict__ w2,
                                                 const float* __restrict__ b2,
                                                 float* __restrict__ tT)
{
    int l = blockIdx.x;
    int lane = threadIdx.x;
    float c0 = rct[l*2+0], c1 = rct[l*2+1];
    float acc[8] = {0,0,0,0,0,0,0,0};
    for (int j = lane; j < 512; j += 64) {
        float hv = fmaxf(c0 * w1[j] + c1 * w1[512+j] + b1[j], 0.f);
        #pragma unroll
        for (int hh = 0; hh < 8; ++hh) acc[hh] += hv * w2[j*8 + hh];
    }
    #pragma unroll
    for (int o = 32; o > 0; o >>= 1)
        #pragma unroll
        for (int hh = 0; hh < 8; ++hh) acc[hh] += __shfl_xor(acc[hh], o, 64);
    if (lane < 8) tT[lane * 1024 + l] = acc[lane] + b2[lane];
}

// ---------------------------------------------------------------------------
// pb precompute: pbl[h][tile][wv][t][lg][la][reg] bf16 = tT[h][rpi[n][p]]
// with n = tile*64+wv*16+la, p = t*16+lg*4+reg. Exactly the attn C-frag order.
// ---------------------------------------------------------------------------
__global__ __launch_bounds__(256) void pb_kernel(const int* __restrict__ rpi,
                                                 const float* __restrict__ tT,
                                                 ushort_t* __restrict__ pbl)
{
    int gid = blockIdx.x * 256 + threadIdx.x;          // 2,097,152 total
    int la   = gid & 15;
    int lg   = (gid >> 4) & 3;
    int t    = (gid >> 6) & 15;
    int wv   = (gid >> 10) & 3;
    int tile = (gid >> 12) & 63;
    int h    = gid >> 18;
    int n  = tile * 64 + wv * 16 + la;
    int p0 = t * 16 + lg * 4;
    int4 r = *(const int4*)&rpi[(size_t)n * PL_ + p0];
    const float* tTh = tT + h * 1024;
    ushort4 o;
    o.x = f2bf(tTh[r.x]);
    o.y = f2bf(tTh[r.y]);
    o.z = f2bf(tTh[r.z]);
    o.w = f2bf(tTh[r.w]);
    *(ushort4*)&pbl[(size_t)gid * 4] = o;
}

// ---------------------------------------------------------------------------
// attn_mfma2: swapped QK^T (A=Kp, B=Q) -> lane-local softmax, shuffle-permuted
// PV A-fragments, no w_lds, 1 barrier. One block per (tile, h, b); 4 waves,
// wave wv owns q-rows r0..r0+15 (r0=wv*16).
// ---------------------------------------------------------------------------
__global__ __launch_bounds__(256, 3) void attn_mfma2(
    const float* __restrict__ q_g,    // raw q  [B*N,256]
    const float* __restrict__ kv_g,   // raw kv [B*N,512]
    const float* __restrict__ kvp_g,  // raw kvp[B*PL,512]
    const ushort_t* __restrict__ pbl, // pool bias, C-frag order
    const float* __restrict__ rpb,    // [8,9]
    const float* __restrict__ qe,     // [8,32]
    const float* __restrict__ temp,   // [8]
    const float* __restrict__ lt,     // [8,32,9]
    const float* __restrict__ lb,     // [8,9]
    ushort_t* __restrict__ outp)      // bf16 [B*N,256]
{
    __shared__ __align__(16) ushort_t qs_lds[64*32];    // 4 KB
    __shared__ __align__(16) ushort_t kp_lds[256*32];   // 16 KB
    __shared__ __align__(16) ushort_t vpT_lds[32*264];  // 16.5 KB
    __shared__ float lt_lds[32*12];
    __shared__ float wloc[64*10];
    __shared__ float wext[64*10];
    __shared__ float invs2[64];
    __shared__ float qe_lds[32];
    __shared__ float rpb_lds[9], lb_lds[9];

    const int tile = blockIdx.x;   // 0..63
    const int hh   = blockIdx.y;   // 0..7
    const int b    = blockIdx.z;   // 0..3
    const int tid  = threadIdx.x;
    const int wv   = tid >> 6;     // wave 0..3
    const int lane = tid & 63;
    const int la   = lane & 15;
    const int lg   = lane >> 4;
    const int r0   = wv * 16;

    // ================= Phase 0: staging =================
    {   // Kp normalize + store (chunk-XOR, key tid&3); VpT store.
        const float* src = kvp_g + ((size_t)(b * PL_ + tid)) * 512 + hh * D_;
        float kk[32]; float ss = 0.f;
        #pragma unroll
        for (int i = 0; i < 8; ++i) {
            float4 v = *(const float4*)&src[i*4];
            kk[i*4+0]=v.x; kk[i*4+1]=v.y; kk[i*4+2]=v.z; kk[i*4+3]=v.w;
            ss += v.x*v.x + v.y*v.y + v.z*v.z + v.w*v.w;
        }
        float inv = rsqrtf(ss + 1e-12f);
        #pragma unroll
        for (int c = 0; c < 4; ++c) {
            short8b v;
            #pragma unroll
            for (int j = 0; j < 8; ++j) v[j] = (short)f2bf(kk[c*8+j] * inv);
            *(short8b*)&kp_lds[tid*32 + ((c ^ (tid & 3)) * 8)] = v;
        }
        #pragma unroll
        for (int d = 0; d < 32; ++d) vpT_lds[d*264 + tid] = f2bf(src[256 + d]);
    }
    if (tid < 64) {  // q rows -> q_scaled bf16 (chunk-XOR, key tid&3), invs2
        int n = tile*64 + tid;
        const float* src = q_g + ((size_t)(b * N_ + n)) * C_ + hh * D_;
        float qq[32]; float ss = 0.f;
        #pragma unroll
        for (int i = 0; i < 8; ++i) {
            float4 v = *(const float4*)&src[i*4];
            qq[i*4+0]=v.x; qq[i*4+1]=v.y; qq[i*4+2]=v.z; qq[i*4+3]=v.w;
            ss += v.x*v.x + v.y*v.y + v.z*v.z + v.w*v.w;
        }
        float inv = rsqrtf(ss + 1e-12f);
        float sp  = log1pf(expf(temp[hh]));
        int y = n >> 6, x = n & 63;
        int ci = 1 + (y > 0) + (y < IMG-1);
        int cj = 1 + (x > 0) + (x < IMG-1);
        float s2 = sp * logf((float)(ci*cj) + (float)PL_);
        invs2[tid] = 1.0f / s2;
        #pragma unroll
        for (int c = 0; c < 4; ++c) {
            short8b v;
            #pragma unroll
            for (int j = 0; j < 8; ++j) {
                int d = c*8 + j;
                v[j] = (short)f2bf((qq[d]*inv + qe[hh*D_ + d]) * s2);
            }
            *(short8b*)&qs_lds[tid*32 + ((c ^ (tid & 3)) * 8)] = v;
        }
    }
    if (tid < 32) {
        #pragma unroll
        for (int l = 0; l < 9; ++l) lt_lds[tid*12 + l] = lt[hh*288 + tid*9 + l];
        qe_lds[tid] = qe[hh*D_ + tid];
    }
    if (tid < 9) { rpb_lds[tid] = rpb[hh*9 + tid]; lb_lds[tid] = lb[hh*9 + tid]; }
    __syncthreads();

    // ================= Phase 1: local logits + extras (wave-local rows) ===
    for (int it = 0; it < 3; ++it) {
        int task = lane + 64*it;
        if (task < 144) {
            int r = task / 9;
            int l = task - r*9;
            int rr = r0 + r;
            int n  = tile*64 + rr;
            int y = n >> 6, x = n & 63;
            int yy = y + l/3 - 1, xx = x + (l%3) - 1;
            bool valid = (yy >= 0 && yy < IMG && xx >= 0 && xx < IMG);
            int m = valid ? (yy*IMG + xx) : 0;
            const float* krow = kv_g + ((size_t)(b*N_ + m)) * 512 + hh*D_;
            float is2 = invs2[rr];
            float s1 = 0.f, s22 = 0.f, ee = 0.f;
            #pragma unroll
            for (int i = 0; i < 8; ++i) {
                float4 kv4 = valid ? *(const float4*)&krow[i*4]
                                   : make_float4(0.f,0.f,0.f,0.f);
                float kvv[4] = {kv4.x, kv4.y, kv4.z, kv4.w};
                #pragma unroll
                for (int j = 0; j < 4; ++j) {
                    int d = i*4 + j;
                    float qsv = bf2f(qs_lds[rr*32 + (((d>>3) ^ (rr&3))<<3) + (d&7)]);
                    s1  += qsv * kvv[j];
                    s22 += kvv[j] * kvv[j];
                    float qnv = qsv * is2 - qe_lds[d];
                    ee  += qnv * lt_lds[d*12 + l];
                }
            }
            wloc[rr*10 + l] = valid ? (s1 * rsqrtf(s22 + 1e-12f) + rpb_lds[l]) : -1e9f;
            wext[rr*10 + l] = ee + lb_lds[l];
        }
    }

    // ================= Phase 2: swapped QK^T (D = S^T) ====================
    // A = Kp rows p = t*16+la; B = Q cols r = r0+la.
    // D[p][r]: thread (la,lg) holds rows p = t*16+lg*4+reg, col r = la.
    const short8b qf = *(const short8b*)&qs_lds[(r0+la)*32 + ((lg ^ (la&3))*8)];
    const ushort_t* pbw = pbl + ((((size_t)hh * 64 + tile) * 4 + wv) * 4096);

    f32x4 acc[16];
    #pragma unroll
    for (int t = 0; t < 16; ++t) {
        ushort4 b4 = *(const ushort4*)&pbw[t*256 + lg*64 + la*4];
        f32x4 c;
        c[0] = bf2f(b4.x); c[1] = bf2f(b4.y); c[2] = bf2f(b4.z); c[3] = bf2f(b4.w);
        short8b kf = *(const short8b*)&kp_lds[(t*16+la)*32 + ((lg ^ (la&3))*8)];
        acc[t] = __builtin_amdgcn_mfma_f32_16x16x32_bf16(kf, qf, c, 0, 0, 0);
    }

    // ================= Phase 3: in-register softmax (row = r0+la) =========
    const int rr = r0 + la;
    float mx = -3.0e38f;
    #pragma unroll
    for (int t = 0; t < 16; ++t)
        #pragma unroll
        for (int reg = 0; reg < 4; ++reg) mx = fmaxf(mx, acc[t][reg]);
    mx = fmaxf(mx, __shfl_xor(mx, 16, 64));
    mx = fmaxf(mx, __shfl_xor(mx, 32, 64));
    float lv[9];
    #pragma unroll
    for (int l = 0; l < 9; ++l) { lv[l] = wloc[rr*10 + l]; mx = fmaxf(mx, lv[l]); }

    float s = 0.f;
    #pragma unroll
    for (int t = 0; t < 16; ++t)
        #pragma unroll
        for (int reg = 0; reg < 4; ++reg) {
            float e = __expf(acc[t][reg] - mx);
            acc[t][reg] = e;
            s += e;
        }
    s += __shfl_xor(s, 16, 64);
    s += __shfl_xor(s, 32, 64);
    float sl = 0.f;
    float el[9];
    #pragma unroll
    for (int l = 0; l < 9; ++l) { el[l] = __expf(lv[l] - mx); sl += el[l]; }
    s += sl;
    const float inv = 1.f / s;
    if (lg == 0) {
        #pragma unroll
        for (int l = 0; l < 9; ++l) wloc[rr*10 + l] = el[l]*inv + wext[rr*10 + l];
    }

    // ================= Phase 4: PV (shuffle-permuted A-frags) =============
    const int src0 = la + 32*(lg & 1);
    const int src1 = src0 + 16;
    const bool hi  = (lg >= 2);

    f32x4 o0 = {0.f,0.f,0.f,0.f}, o1 = {0.f,0.f,0.f,0.f};
    #pragma unroll
    for (int kk = 0; kk < 8; ++kk) {
        unsigned A0 = pk2(acc[2*kk][0]*inv,   acc[2*kk][1]*inv);
        unsigned A1 = pk2(acc[2*kk][2]*inv,   acc[2*kk][3]*inv);
        unsigned B0 = pk2(acc[2*kk+1][0]*inv, acc[2*kk+1][1]*inv);
        unsigned B1 = pk2(acc[2*kk+1][2]*inv, acc[2*kk+1][3]*inv);
        unsigned xa0 = __shfl(A0, src0, 64), xb0 = __shfl(B0, src0, 64);
        unsigned xa1 = __shfl(A1, src0, 64), xb1 = __shfl(B1, src0, 64);
        unsigned ya0 = __shfl(A0, src1, 64), yb0 = __shfl(B0, src1, 64);
        unsigned ya1 = __shfl(A1, src1, 64), yb1 = __shfl(B1, src1, 64);
        union { unsigned u[4]; short8b v; } wf;
        wf.u[0] = hi ? xb0 : xa0;
        wf.u[1] = hi ? xb1 : xa1;
        wf.u[2] = hi ? yb0 : ya0;
        wf.u[3] = hi ? yb1 : ya1;
        short8b vf0 = *(const short8b*)&vpT_lds[la*264      + kk*32 + lg*8];
        short8b vf1 = *(const short8b*)&vpT_lds[(16+la)*264 + kk*32 + lg*8];
        o0 = __builtin_amdgcn_mfma_f32_16x16x32_bf16(wf.v, vf0, o0, 0, 0, 0);
        o1 = __builtin_amdgcn_mfma_f32_16x16x32_bf16(wf.v, vf1, o1, 0, 0, 0);
    }
    #pragma unroll
    for (int reg = 0; reg < 4; ++reg) {
        int r2 = r0 + lg*4 + reg;
        int n  = tile*64 + r2;
        int y = n >> 6, x = n & 63;
        float v0 = o0[reg], v1 = o1[reg];
        #pragma unroll
        for (int l = 0; l < 9; ++l) {
            int yy = y + l/3 - 1, xx = x + (l%3) - 1;
            if (yy >= 0 && yy < IMG && xx >= 0 && xx < IMG) {
                float wl = wloc[r2*10 + l];
                const float* vrow = kv_g + ((size_t)(b*N_ + yy*IMG + xx))*512 + 256 + hh*D_;
                v0 += wl * vrow[la];
                v1 += wl * vrow[16 + la];
            }
        }
        ushort_t* orow = outp + ((size_t)(b*N_ + n)) * C_ + hh*D_;
        orow[la]      = f2bf(v0);
        orow[16 + la] = f2bf(v1);
    }
}

// ---------------------------------------------------------------------------
extern "C" void kernel_launch(void* const* d_in, const int* in_sizes, int n_in,
                              void* d_out, int out_size, void* d_ws, size_t ws_size,
                              hipStream_t stream) {
    const float* x    = (const float*)d_in[0];
    const float* rct  = (const float*)d_in[1];
    const int*   rpi  = (const int*)  d_in[2];
    const float* q_w  = (const float*)d_in[3];
    const float* q_b  = (const float*)d_in[4];
    const float* kv_w = (const float*)d_in[5];
    const float* kv_b = (const float*)d_in[6];
    const float* temp = (const float*)d_in[7];
    const float* qe   = (const float*)d_in[8];
    const float* sr_w = (const float*)d_in[9];
    const float* sr_b = (const float*)d_in[10];
    const float* ng   = (const float*)d_in[11];
    const float* nb   = (const float*)d_in[12];
    const float* c1w  = (const float*)d_in[13];
    const float* c1b  = (const float*)d_in[14];
    const float* c2w  = (const float*)d_in[15];
    const float* c2b  = (const float*)d_in[16];
    const float* rpb  = (const float*)d_in[17];
    const float* lt   = (const float*)d_in[18];
    const float* lb   = (const float*)d_in[19];
    const float* p_w  = (const float*)d_in[20];
    const float* p_b  = (const float*)d_in[21];
    float* out = (float*)d_out;

    float* ws = (float*)d_ws;
    const size_t MN = (size_t)B_ * N_;               // 16384
    float* buf_q   = ws;                             // [MN,256] raw q f32
    float* buf_kv  = buf_q   + MN * 256;             // [MN,512] raw k|v f32
    float* buf_sr  = buf_kv  + MN * 512;             // [MN,256] gelu(sr) f32 -> later pbl
    float* buf_xs  = buf_sr  + MN * 256;             // [B*PL,256] region (bf16 used)
    float* buf_kvp = buf_xs  + (size_t)B_*PL_*256;   // [B*PL,512] f32
    float* buf_t   = buf_kvp + (size_t)B_*PL_*512;   // [8,1024]
    ushort_t* bf_base = (ushort_t*)(buf_t + 8*1024);
    ushort_t* x_bf   = bf_base;                      // [MN,256] bf16
    ushort_t* pre_bf = x_bf   + MN * 256;            // [MN,256] bf16 attn out
    ushort_t* qwT    = pre_bf + MN * 256;            // [256,256]
    ushort_t* kvwT   = qwT    + 256*256;             // [512,256]
    ushort_t* srwT   = kvwT   + 512*256;             // [256,256]
    ushort_t* pwT    = srwT   + 256*256;             // [256,256]
    ushort_t* xs_bf  = (ushort_t*)buf_xs;            // [B*PL,256] bf16
    ushort_t* pbl    = (ushort_t*)buf_sr;            // [8*64*4*16*4*16*4] bf16 (16.8MB)

    const int M = (int)MN;  // 16384

    // conversions
    tobf16_kernel<<<(M*256/8 + 255)/256, 256, 0, stream>>>(x, x_bf, M*256/8);
    wtrans_kernel<<<(256*256/8 + 255)/256, 256, 0, stream>>>(q_w,  qwT,  256, 256);
    wtrans_kernel<<<(512*256/8 + 255)/256, 256, 0, stream>>>(kv_w, kvwT, 256, 512);
    wtrans_kernel<<<(256*256/8 + 255)/256, 256, 0, stream>>>(sr_w, srwT, 256, 256);
    wtrans_kernel<<<(256*256/8 + 255)/256, 256, 0, stream>>>(p_w,  pwT,  256, 256);

    // big GEMMs (bf16 MFMA, LDS-staged B)
    gemm_mfma<0><<<dim3(256/64, M/128), 256, 0, stream>>>(x_bf, qwT,  q_b,  buf_q,  M, 256);
    gemm_mfma<0><<<dim3(512/64, M/128), 256, 0, stream>>>(x_bf, kvwT, kv_b, buf_kv, M, 512);
    gemm_mfma<1><<<dim3(256/64, M/128), 256, 0, stream>>>(x_bf, srwT, sr_b, buf_sr, M, 256);

    pool_ln_kernel<<<B_ * PL_, 256, 0, stream>>>(buf_sr, ng, nb, xs_bf);
    gemm_mfma<0><<<dim3(512/64, (B_*PL_)/128), 256, 0, stream>>>(xs_bf, kvwT, kv_b,
                                                                 buf_kvp, B_*PL_, 512);
    cpb_kernel<<<1024, 64, 0, stream>>>(rct, c1w, c1b, c2w, c2b, buf_t);
    // pb AFTER pool_ln (pbl aliases buf_sr) and AFTER cpb (reads tT)
    pb_kernel<<<8192, 256, 0, stream>>>(rpi, buf_t, pbl);

    attn_mfma2<<<dim3(64, 8, 4), 256, 0, stream>>>(buf_q, buf_kv, buf_kvp, pbl,
                                                   rpb, qe, temp, lt, lb, pre_bf);

    gemm_mfma<0><<<dim3(256/64, M/128), 256, 0, stream>>>(pre_bf, pwT, p_b, out, M, 256);
}